// Round 4
// baseline (3750.508 us; speedup 1.0000x reference)
//
#include <hip/hip_runtime.h>

#define NB 8
#define NN 8192
#define ND 256
#define NPOINT 2048
#define NSAMPLE 32
#define WNET 16
#define INCH 259          // 3 + 256
#define OUTCH 512
#define KPAD 4160         // 259*16 = 4144 padded to 4160 (= 65*64)

typedef short short8 __attribute__((ext_vector_type(8)));
typedef float float4v __attribute__((ext_vector_type(4)));
typedef unsigned long long u64;

__device__ __forceinline__ unsigned short f2bf(float x){
  unsigned u = __float_as_uint(x);
  u = (u + 0x7FFFu + ((u >> 16) & 1u)) >> 16;
  return (unsigned short)u;
}
__device__ __forceinline__ float bf2f(unsigned short v){
  return __uint_as_float(((unsigned)v) << 16);
}

// wave64 max of packed u64 via DPP. Result valid in lane 63.
__device__ __forceinline__ u64 wave_max_dpp(u64 k){
#define DPPSTEP(ctrl) {                                                        \
    unsigned lo = (unsigned)k, hi = (unsigned)(k >> 32);                       \
    unsigned olo = (unsigned)__builtin_amdgcn_update_dpp(0, (int)lo, ctrl, 0xf, 0xf, true); \
    unsigned ohi = (unsigned)__builtin_amdgcn_update_dpp(0, (int)hi, ctrl, 0xf, 0xf, true); \
    u64 o = (((u64)ohi) << 32) | olo;                                          \
    if (o > k) k = o; }
  DPPSTEP(0x111)  // row_shr:1
  DPPSTEP(0x112)  // row_shr:2
  DPPSTEP(0x114)  // row_shr:4
  DPPSTEP(0x118)  // row_shr:8
  DPPSTEP(0x142)  // row_bcast15
  DPPSTEP(0x143)  // row_bcast31
#undef DPPSTEP
  return k;
}

// max over lanes 0..15 (all rows hold identical data); result in lane 15.
__device__ __forceinline__ u64 row16_max_dpp(u64 k){
#define DPPSTEP(ctrl) {                                                        \
    unsigned lo = (unsigned)k, hi = (unsigned)(k >> 32);                       \
    unsigned olo = (unsigned)__builtin_amdgcn_update_dpp(0, (int)lo, ctrl, 0xf, 0xf, true); \
    unsigned ohi = (unsigned)__builtin_amdgcn_update_dpp(0, (int)hi, ctrl, 0xf, 0xf, true); \
    u64 o = (((u64)ohi) << 32) | olo;                                          \
    if (o > k) k = o; }
  DPPSTEP(0x111)
  DPPSTEP(0x112)
  DPPSTEP(0x114)
  DPPSTEP(0x118)
#undef DPPSTEP
  return k;
}

// ---------------------------------------------------------------------------
// 0. Morton sort: per batch, bitonic sort 8192 points by 30-bit Morton key.
// ---------------------------------------------------------------------------
__device__ __forceinline__ unsigned p1b2(unsigned v){
  v &= 0x3FFu;
  v = (v | (v << 16)) & 0x030000FFu;
  v = (v | (v << 8))  & 0x0300F00Fu;
  v = (v | (v << 4))  & 0x030C30C3u;
  v = (v | (v << 2))  & 0x09249249u;
  return v;
}

__global__ __launch_bounds__(1024) void morton_sort_kernel(
    const float* __restrict__ xyz, float* __restrict__ sx, float* __restrict__ sy,
    float* __restrict__ sz, int* __restrict__ sorig){
  __shared__ u64 arr[NN];          // 64 KB
  const int b = blockIdx.x, t = threadIdx.x;
  const float* xp = xyz + (size_t)b * 3 * NN;
#pragma unroll
  for (int j = 0; j < 8; j++){
    int n = t + j * 1024;
    float x = xp[n], y = xp[NN + n], z = xp[2 * NN + n];
    unsigned qx = (unsigned)fminf(1023.f, fmaxf(0.f, (x + 6.f) * 85.25f));
    unsigned qy = (unsigned)fminf(1023.f, fmaxf(0.f, (y + 6.f) * 85.25f));
    unsigned qz = (unsigned)fminf(1023.f, fmaxf(0.f, (z + 6.f) * 85.25f));
    unsigned key = (p1b2(qz) << 2) | (p1b2(qy) << 1) | p1b2(qx);
    arr[n] = (((u64)key) << 13) | (unsigned)n;
  }
  __syncthreads();
  for (int k = 2; k <= NN; k <<= 1){
    for (int j = k >> 1; j >= 1; j >>= 1){
#pragma unroll
      for (int pi = 0; pi < 4; pi++){
        int p = t + pi * 1024;
        int lo = ((p & ~(j - 1)) << 1) | (p & (j - 1));
        int hi = lo | j;
        bool asc = (lo & k) == 0;
        u64 a = arr[lo], c = arr[hi];
        if (asc ? (a > c) : (c > a)){ arr[lo] = c; arr[hi] = a; }
      }
      __syncthreads();
    }
  }
#pragma unroll
  for (int j = 0; j < 8; j++){
    int n = t + j * 1024;
    int orig = (int)(arr[n] & 8191u);
    sx[(size_t)b * NN + n] = xp[orig];
    sy[(size_t)b * NN + n] = xp[NN + orig];
    sz[(size_t)b * NN + n] = xp[2 * NN + orig];
    sorig[(size_t)b * NN + n] = orig;
  }
}

// ---------------------------------------------------------------------------
// 1. FPS: geometric screening + DPP reduce + parallel LDS exchange.
//    Winners logged to LDS seq[], written back coalesced after the loop.
//    Distance math identical to numpy: (dx*dx+dy*dy)+dz*dz, contract off.
// ---------------------------------------------------------------------------
__global__ __launch_bounds__(1024) void fps_kernel(
    const float* __restrict__ sxg, const float* __restrict__ syg,
    const float* __restrict__ szg, const int* __restrict__ sorigg,
    float* __restrict__ out0, float* __restrict__ out2, float* __restrict__ wnew){
#pragma clang fp contract(off)
  __shared__ float4v pxyz[NN];     // 128 KB
  __shared__ u64 seq[NPOINT];      // 16 KB winner log
  __shared__ u64 red[2][16];       // double-buffered per-wave winners
  __shared__ int s_pos0;
  const int b = blockIdx.x, t = threadIdx.x;
  const int lane = t & 63, w = t >> 6;
  const int base = w * 512 + lane * 8;
  const float* gx = sxg + (size_t)b * NN;
  const float* gy = syg + (size_t)b * NN;
  const float* gz = szg + (size_t)b * NN;
  const int*   go = sorigg + (size_t)b * NN;

  float x[8], y[8], z[8], ld[8]; int so[8];
#pragma unroll
  for (int j = 0; j < 8; j++){
    int n = base + j;
    x[j] = gx[n]; y[j] = gy[n]; z[j] = gz[n]; so[j] = go[n];
    pxyz[n] = (float4v){x[j], y[j], z[j], 0.f};
    if (so[j] == 0) s_pos0 = n;
    ld[j] = 1e10f;
  }
  // chunk bounding sphere (center = AABB mid, radius inflated for fp safety)
  float mnx = x[0], mxx = x[0], mny = y[0], mxy = y[0], mnz = z[0], mxz = z[0];
#pragma unroll
  for (int j = 1; j < 8; j++){
    mnx = fminf(mnx, x[j]); mxx = fmaxf(mxx, x[j]);
    mny = fminf(mny, y[j]); mxy = fmaxf(mxy, y[j]);
    mnz = fminf(mnz, z[j]); mxz = fmaxf(mxz, z[j]);
  }
  const float ccx = (mnx + mxx) * 0.5f, ccy = (mny + mxy) * 0.5f, ccz = (mnz + mxz) * 0.5f;
  float R2 = 0.f;
#pragma unroll
  for (int j = 0; j < 8; j++){
    float dx = x[j] - ccx, dy = y[j] - ccy, dz = z[j] - ccz;
    R2 = fmaxf(R2, (dx * dx + dy * dy) + dz * dz);
  }
  const float R = sqrtf(R2) * 1.001f + 1e-7f;
  float thr = 3e38f;            // force compute on first iteration
  u64 wkey = 0;                 // cached wave winner (valid in lane 63)
  __syncthreads();

  int pos = s_pos0;
  float4v c4 = pxyz[pos];
  float cx = c4[0], cy = c4[1], cz = c4[2];
  if (t == 0) seq[0] = (((u64)8191) << 13) | (unsigned)pos;   // orig=0

  for (int i = 1; i < NPOINT; i++){
    float qdx = cx - ccx, qdy = cy - ccy, qdz = cz - ccz;
    float q = (qdx * qdx + qdy * qdy) + qdz * qdz;
    if (__any(q < thr)){
      float bv = -1.f; int bo = 0, bp = 0;
#pragma unroll
      for (int j = 0; j < 8; j++){
        float dx = x[j] - cx, dy = y[j] - cy, dz = z[j] - cz;
        float d  = (dx * dx + dy * dy) + dz * dz;     // numpy order, no fma
        float nd = fminf(ld[j], d);
        ld[j] = nd;
        bool better = (nd > bv) || (nd == bv && so[j] < bo);
        bv = better ? nd : bv;
        bo = better ? so[j] : bo;
        bp = better ? (base + j) : bp;
      }
      float sr = sqrtf(bv) * 1.001f + R;
      thr = sr * sr;
      u64 k2 = (((u64)__float_as_uint(bv)) << 26) | (((u64)(8191 - bo)) << 13) | (unsigned)bp;
      wkey = wave_max_dpp(k2);                        // lane 63 holds wave max
    }
    if (lane == 63) red[i & 1][w] = wkey;
    __syncthreads();
    u64 rv = red[i & 1][lane & 15];
    rv = row16_max_dpp(rv);                           // lane 15 holds winner
    unsigned rlo = (unsigned)__builtin_amdgcn_readlane((int)(unsigned)rv, 15);
    unsigned rhi = (unsigned)__builtin_amdgcn_readlane((int)(unsigned)(rv >> 32), 15);
    u64 v = (((u64)rhi) << 32) | rlo;                 // wave-uniform (SGPR)
    pos = (int)(v & 8191u);
    float4v n4 = pxyz[pos];                           // uniform broadcast read
    cx = n4[0]; cy = n4[1]; cz = n4[2];
    if (t == 0) seq[i] = v;
  }
  __syncthreads();
  // coalesced writeback of the 2048 winners
  for (int k = t; k < NPOINT; k += 1024){
    u64 v = seq[k];
    int p = (int)(v & 8191u);
    int orig = 8191 - (int)((v >> 13) & 8191u);
    float4v pv = pxyz[p];
    out2[b * NPOINT + k] = (float)orig;
    out0[(size_t)b * 3 * NPOINT + k]              = pv[0];
    out0[(size_t)b * 3 * NPOINT + NPOINT + k]     = pv[1];
    out0[(size_t)b * 3 * NPOINT + 2 * NPOINT + k] = pv[2];
    float* wp = wnew + ((size_t)b * NPOINT + k) * 3;
    wp[0] = pv[0]; wp[1] = pv[1]; wp[2] = pv[2];
  }
}

// ---------------------------------------------------------------------------
// 2. transpose points [B,256,8192] f32 -> [B,8192,256] bf16
// ---------------------------------------------------------------------------
__global__ __launch_bounds__(1024) void transpose_points(
    const float* __restrict__ pts, unsigned short* __restrict__ ptsT){
  __shared__ float tile[64][65];
  const int b  = blockIdx.z;
  const int n0 = blockIdx.x * 64;
  const int d0 = blockIdx.y * 64;
  const int tx = threadIdx.x, ty = threadIdx.y;
  const float* src = pts + ((size_t)b * ND + d0) * NN + n0;
#pragma unroll
  for (int j = 0; j < 4; j++){
    int d = ty + j * 16;
    tile[d][tx] = src[(size_t)d * NN + tx];
  }
  __syncthreads();
  unsigned short* dst = ptsT + ((size_t)b * NN + n0) * ND + d0;
#pragma unroll
  for (int j = 0; j < 4; j++){
    int n = ty + j * 16;
    dst[(size_t)n * ND + tx] = f2bf(tile[tx][n]);
  }
}

// ---------------------------------------------------------------------------
// 3. lin_w [512,4144] f32 -> [512,4160] bf16 (pad zero)
// ---------------------------------------------------------------------------
__global__ __launch_bounds__(256) void convert_linw(
    const float* __restrict__ lw, unsigned short* __restrict__ out){
  int i = blockIdx.x * 256 + threadIdx.x;
  if (i >= OUTCH * KPAD) return;
  int o = i / KPAD, f = i - o * KPAD;
  float v = (f < WNET * INCH) ? lw[(size_t)o * (WNET * INCH) + f] : 0.f;
  out[i] = f2bf(v);
}

// ---------------------------------------------------------------------------
// 4. kNN: one 256-thread WG per query. radix-select rank-32 threshold,
//    stable (key,idx) tie-break for boundary elements.
// ---------------------------------------------------------------------------
__device__ __forceinline__ void find_bin64(const unsigned* hist, unsigned r,
                                           unsigned* outB, unsigned* outC, int lane){
  unsigned h0 = hist[lane * 4 + 0], h1 = hist[lane * 4 + 1];
  unsigned h2 = hist[lane * 4 + 2], h3 = hist[lane * 4 + 3];
  unsigned s4 = h0 + h1 + h2 + h3;
  unsigned sc = s4;
#pragma unroll
  for (int off = 1; off < 64; off <<= 1){
    unsigned o = __shfl_up(sc, off, 64);
    if (lane >= off) sc += o;
  }
  unsigned cum = sc - s4;
  if (cum < r && cum + h0 >= r){ *outB = lane * 4 + 0; *outC = cum; } cum += h0;
  if (cum < r && cum + h1 >= r){ *outB = lane * 4 + 1; *outC = cum; } cum += h1;
  if (cum < r && cum + h2 >= r){ *outB = lane * 4 + 2; *outC = cum; } cum += h2;
  if (cum < r && cum + h3 >= r){ *outB = lane * 4 + 3; *outC = cum; } cum += h3;
}

__global__ __launch_bounds__(256) void knn_kernel(const float* __restrict__ xyz,
    const float* __restrict__ newxyz, int* __restrict__ ws_idx){
  __shared__ unsigned key[NN];
  __shared__ unsigned hist[256];
  __shared__ int s_sel[48];
  __shared__ unsigned candk[256];
  __shared__ int candi[256];
  __shared__ int s_selcnt, s_candcnt;
  __shared__ unsigned s_info[4];
  const int q = blockIdx.x;
  const int b = q >> 11;
  const int t = threadIdx.x;
  const float* xp = xyz + (size_t)b * 3 * NN;
  float qx = newxyz[q * 3], qy = newxyz[q * 3 + 1], qz = newxyz[q * 3 + 2];
  float qq = qx * qx + qy * qy + qz * qz;
#pragma unroll 4
  for (int j = 0; j < 32; j++){
    int n = t + j * 256;
    float px = xp[n], py = xp[NN + n], pz = xp[2 * NN + n];
    float pp = px * px + py * py + pz * pz;
    float d  = qq + pp - 2.f * (qx * px + qy * py + qz * pz);
    unsigned u = __float_as_uint(d);
    u ^= (u & 0x80000000u) ? 0xFFFFFFFFu : 0x80000000u;
    key[n] = u;
  }
  hist[t] = 0;
  if (t == 0){ s_selcnt = 0; s_candcnt = 0; }
  __syncthreads();
#pragma unroll 4
  for (int j = 0; j < 32; j++){
    int n = t + j * 256;
    atomicAdd(&hist[key[n] >> 24], 1u);
  }
  __syncthreads();
  if (t < 64) find_bin64(hist, NSAMPLE, &s_info[0], &s_info[1], t);
  __syncthreads();
  unsigned B1 = s_info[0], c0 = s_info[1];
  hist[t] = 0;
  __syncthreads();
#pragma unroll 4
  for (int j = 0; j < 32; j++){
    int n = t + j * 256;
    unsigned u = key[n];
    if ((u >> 24) == B1) atomicAdd(&hist[(u >> 16) & 0xFFu], 1u);
  }
  __syncthreads();
  if (t < 64) find_bin64(hist, NSAMPLE - c0, &s_info[2], &s_info[3], t);
  __syncthreads();
  unsigned T16 = (B1 << 8) | s_info[2];
  int c01 = (int)(c0 + s_info[3]);
#pragma unroll 4
  for (int j = 0; j < 32; j++){
    int n = t + j * 256;
    unsigned k16 = key[n] >> 16;
    if (k16 < T16){
      int p = atomicAdd(&s_selcnt, 1);
      s_sel[p] = n;
    } else if (k16 == T16){
      int p = atomicAdd(&s_candcnt, 1);
      if (p < 256){ candk[p] = key[n]; candi[p] = n; }
    }
  }
  __syncthreads();
  const int m = NSAMPLE - c01;
  const int L = s_candcnt;
  if (t < 64){
    u64 prev = 0;
    for (int r = 0; r < m; r++){
      u64 best = ~0ULL;
      if (L <= 256){
        for (int j = t; j < L; j += 64){
          u64 pk = (((u64)candk[j]) << 32) | (unsigned)candi[j];
          if (pk > prev && pk < best) best = pk;
        }
      } else {
        for (int j = 0; j < 128; j++){
          int n = t + j * 64;
          unsigned u = key[n];
          if ((u >> 16) == T16){
            u64 pk = (((u64)u) << 32) | (unsigned)n;
            if (pk > prev && pk < best) best = pk;
          }
        }
      }
#pragma unroll
      for (int off = 32; off > 0; off >>= 1){
        u64 o = __shfl_down(best, off, 64);
        if (o < best) best = o;
      }
      best = __shfl(best, 0, 64);
      if (t == 0) s_sel[c01 + r] = (int)(best & 0xFFFFFFFFu);
      prev = best;
    }
  }
  __syncthreads();
  if (t < NSAMPLE) ws_idx[(size_t)q * NSAMPLE + t] = s_sel[t];
}

// ---------------------------------------------------------------------------
// 5. gather + WeightNet + per-point aggregation -> Agg[16384][4160] bf16
// ---------------------------------------------------------------------------
__global__ __launch_bounds__(256) void agg_kernel(
    const float* __restrict__ xyz, const float* __restrict__ newxyz,
    const int* __restrict__ ws_idx, const unsigned short* __restrict__ ptsT,
    const float* __restrict__ w1, const float* __restrict__ b1,
    const float* __restrict__ w2, const float* __restrict__ b2,
    const float* __restrict__ w3, const float* __restrict__ b3,
    unsigned short* __restrict__ agg){
  __shared__ float feat[32][257];
  __shared__ float __align__(16) wgt[32][16];
  __shared__ float xyzn[32][4];
  __shared__ int nid[32];
  const int q = blockIdx.x;
  const int b = q >> 11;
  const int t = threadIdx.x;
  if (t < 32) nid[t] = ws_idx[(size_t)q * NSAMPLE + t];
  __syncthreads();
  if (t < 32){
    int n = nid[t];
    const float* xp = xyz + (size_t)b * 3 * NN;
    float qx = newxyz[q * 3], qy = newxyz[q * 3 + 1], qz = newxyz[q * 3 + 2];
    float xn = xp[n] - qx, yn = xp[NN + n] - qy, zn = xp[2 * NN + n] - qz;
    xyzn[t][0] = xn; xyzn[t][1] = yn; xyzn[t][2] = zn;
    float h1[8], h2[8];
#pragma unroll
    for (int i = 0; i < 8; i++)
      h1[i] = fmaxf(0.f, w1[i * 3] * xn + w1[i * 3 + 1] * yn + w1[i * 3 + 2] * zn + b1[i]);
#pragma unroll
    for (int i = 0; i < 8; i++){
      float a = b2[i];
#pragma unroll
      for (int j = 0; j < 8; j++) a += w2[i * 8 + j] * h1[j];
      h2[i] = fmaxf(0.f, a);
    }
#pragma unroll
    for (int i = 0; i < 16; i++){
      float a = b3[i];
#pragma unroll
      for (int j = 0; j < 8; j++) a += w3[i * 8 + j] * h2[j];
      wgt[t][i] = fmaxf(0.f, a);
    }
  }
#pragma unroll
  for (int j = 0; j < 4; j++){
    int c = t + 256 * j;
    int row = c >> 5, col = c & 31;
    const uint4* src = (const uint4*)(ptsT + ((size_t)b * NN + nid[row]) * ND) + col;
    uint4 v = *src;
    float* dstf = &feat[row][col * 8];
    dstf[0] = bf2f((unsigned short)(v.x & 0xFFFF)); dstf[1] = bf2f((unsigned short)(v.x >> 16));
    dstf[2] = bf2f((unsigned short)(v.y & 0xFFFF)); dstf[3] = bf2f((unsigned short)(v.y >> 16));
    dstf[4] = bf2f((unsigned short)(v.z & 0xFFFF)); dstf[5] = bf2f((unsigned short)(v.z >> 16));
    dstf[6] = bf2f((unsigned short)(v.w & 0xFFFF)); dstf[7] = bf2f((unsigned short)(v.w >> 16));
  }
  __syncthreads();
  for (int c = t; c < INCH; c += 256){
    const float* npb; int stride;
    if (c < 3){ npb = &xyzn[0][c]; stride = 4; }
    else      { npb = &feat[0][c - 3]; stride = 257; }
    float acc[16];
#pragma unroll
    for (int i = 0; i < 16; i++) acc[i] = 0.f;
    for (int k = 0; k < 32; k++){
      float v = npb[k * stride];
      const float4v* wr = (const float4v*)(&wgt[k][0]);
      float4v a0 = wr[0], a1 = wr[1], a2 = wr[2], a3 = wr[3];
      acc[0]  += v * a0[0]; acc[1]  += v * a0[1]; acc[2]  += v * a0[2]; acc[3]  += v * a0[3];
      acc[4]  += v * a1[0]; acc[5]  += v * a1[1]; acc[6]  += v * a1[2]; acc[7]  += v * a1[3];
      acc[8]  += v * a2[0]; acc[9]  += v * a2[1]; acc[10] += v * a2[2]; acc[11] += v * a2[3];
      acc[12] += v * a3[0]; acc[13] += v * a3[1]; acc[14] += v * a3[2]; acc[15] += v * a3[3];
    }
    unsigned r[8];
#pragma unroll
    for (int p = 0; p < 8; p++)
      r[p] = (unsigned)f2bf(acc[2 * p]) | ((unsigned)f2bf(acc[2 * p + 1]) << 16);
    uint4* dst = (uint4*)(agg + (size_t)q * KPAD + c * WNET);
    uint4 v0 = {r[0], r[1], r[2], r[3]};
    uint4 v1 = {r[4], r[5], r[6], r[7]};
    dst[0] = v0; dst[1] = v1;
  }
  if (t == 3){
    uint4 z = {0, 0, 0, 0};
    uint4* dst = (uint4*)(agg + (size_t)q * KPAD + WNET * INCH);
    dst[0] = z; dst[1] = z;
  }
}

// ---------------------------------------------------------------------------
// 6. GEMM: Out[16384,512] = Agg[16384,4160] * lin_w[512,4160]^T + bias,
//    LeakyReLU, transposed store to [B,512,2048].
// ---------------------------------------------------------------------------
#define BM 128
#define BN 128
#define BK 64
__global__ __launch_bounds__(256) void gemm_kernel(
    const unsigned short* __restrict__ A, const unsigned short* __restrict__ W,
    const float* __restrict__ bias, float* __restrict__ out1){
  __shared__ short __align__(16) As[BM * BK];
  __shared__ short __align__(16) Ws[BN * BK];
  const int t = threadIdx.x;
  const int m0 = blockIdx.x * BM;
  const int n0 = blockIdx.y * BN;
  const int wave = t >> 6, lane = t & 63;
  const int wm = (wave >> 1) * 64, wn = (wave & 1) * 64;
  const int lrow = lane & 15, quad = lane >> 4;
  float4v acc[4][4];
#pragma unroll
  for (int i = 0; i < 4; i++)
#pragma unroll
    for (int j = 0; j < 4; j++) acc[i][j] = (float4v){0.f, 0.f, 0.f, 0.f};

  for (int k0 = 0; k0 < KPAD; k0 += BK){
#pragma unroll
    for (int j = 0; j < 4; j++){
      int chunk = t + 256 * j;
      int row = chunk >> 3, c = chunk & 7;
      uint4 v = *(const uint4*)(A + (size_t)(m0 + row) * KPAD + k0 + c * 8);
      *(uint4*)&As[chunk * 8] = v;
    }
#pragma unroll
    for (int j = 0; j < 4; j++){
      int chunk = t + 256 * j;
      int row = chunk >> 3, c = chunk & 7;
      uint4 v = *(const uint4*)(W + (size_t)(n0 + row) * KPAD + k0 + c * 8);
      *(uint4*)&Ws[chunk * 8] = v;
    }
    __syncthreads();
#pragma unroll
    for (int kk = 0; kk < 2; kk++){
      short8 a[4], w[4];
      int kof = kk * 32 + quad * 8;
#pragma unroll
      for (int i = 0; i < 4; i++){
        a[i] = *(const short8*)&As[(wm + i * 16 + lrow) * BK + kof];
        w[i] = *(const short8*)&Ws[(wn + i * 16 + lrow) * BK + kof];
      }
#pragma unroll
      for (int i = 0; i < 4; i++)
#pragma unroll
        for (int j = 0; j < 4; j++)
          acc[i][j] = __builtin_amdgcn_mfma_f32_16x16x32_bf16(a[i], w[j], acc[i][j], 0, 0, 0);
    }
    __syncthreads();
  }
#pragma unroll
  for (int i = 0; i < 4; i++){
#pragma unroll
    for (int j = 0; j < 4; j++){
      int m = m0 + wm + i * 16 + quad * 4;
      int n = n0 + wn + j * 16 + lrow;
      float bv = bias[n];
      int bb = m >> 11, s = m & 2047;
      float* dst = out1 + ((size_t)bb * OUTCH + n) * NPOINT + s;
      float4v v = acc[i][j];
      float4v r;
#pragma unroll
      for (int e = 0; e < 4; e++){
        float x = v[e] + bv;
        r[e] = x > 0.f ? x : 0.1f * x;
      }
      *(float4v*)dst = r;
    }
  }
}

// ---------------------------------------------------------------------------
extern "C" void kernel_launch(void* const* d_in, const int* in_sizes, int n_in,
                              void* d_out, int out_size, void* d_ws, size_t ws_size,
                              hipStream_t stream) {
  const float* xyz    = (const float*)d_in[0];
  const float* points = (const float*)d_in[1];
  const float* w1 = (const float*)d_in[2];
  const float* b1 = (const float*)d_in[3];
  const float* w2 = (const float*)d_in[4];
  const float* b2 = (const float*)d_in[5];
  const float* w3 = (const float*)d_in[6];
  const float* b3 = (const float*)d_in[7];
  const float* lin_w = (const float*)d_in[8];
  const float* lin_b = (const float*)d_in[9];

  float* out0 = (float*)d_out;
  float* out1 = out0 + (size_t)NB * 3 * NPOINT;
  float* out2 = out1 + (size_t)NB * OUTCH * NPOINT;

  char* ws = (char*)d_ws;
  float* ws_newxyz = (float*)ws;                                   size_t o = (size_t)NB * NPOINT * 3 * 4;
  int* ws_idx = (int*)(ws + o);                                    o += (size_t)NB * NPOINT * NSAMPLE * 4;
  unsigned short* ws_ptsT = (unsigned short*)(ws + o);             o += (size_t)NB * NN * ND * 2;
  unsigned short* ws_lw = (unsigned short*)(ws + o);               o += (size_t)OUTCH * KPAD * 2;
  unsigned short* ws_agg = (unsigned short*)(ws + o);              o += (size_t)NB * NPOINT * KPAD * 2;
  float* ws_sx = (float*)(ws + o);                                 o += (size_t)NB * NN * 4;
  float* ws_sy = (float*)(ws + o);                                 o += (size_t)NB * NN * 4;
  float* ws_sz = (float*)(ws + o);                                 o += (size_t)NB * NN * 4;
  int*   ws_so = (int*)(ws + o);                                   o += (size_t)NB * NN * 4;

  morton_sort_kernel<<<NB, 1024, 0, stream>>>(xyz, ws_sx, ws_sy, ws_sz, ws_so);
  fps_kernel<<<NB, 1024, 0, stream>>>(ws_sx, ws_sy, ws_sz, ws_so, out0, out2, ws_newxyz);
  transpose_points<<<dim3(NN / 64, ND / 64, NB), dim3(64, 16), 0, stream>>>(points, ws_ptsT);
  convert_linw<<<(OUTCH * KPAD + 255) / 256, 256, 0, stream>>>(lin_w, ws_lw);
  knn_kernel<<<NB * NPOINT, 256, 0, stream>>>(xyz, ws_newxyz, ws_idx);
  agg_kernel<<<NB * NPOINT, 256, 0, stream>>>(xyz, ws_newxyz, ws_idx, ws_ptsT,
                                              w1, b1, w2, b2, w3, b3, ws_agg);
  gemm_kernel<<<dim3(NB * NPOINT / BM, OUTCH / BN), 256, 0, stream>>>(ws_agg, ws_lw, lin_b, out1);
}

// Round 5
// 3038.706 us; speedup vs baseline: 1.2342x; 1.2342x over previous
//
#include <hip/hip_runtime.h>

#define NB 8
#define NN 8192
#define ND 256
#define NPOINT 2048
#define NSAMPLE 32
#define WNET 16
#define INCH 259          // 3 + 256
#define OUTCH 512
#define KPAD 4160         // 259*16 = 4144 padded to 4160

typedef short short8 __attribute__((ext_vector_type(8)));
typedef float float4v __attribute__((ext_vector_type(4)));
typedef unsigned long long u64;

__device__ __forceinline__ unsigned short f2bf(float x){
  unsigned u = __float_as_uint(x);
  u = (u + 0x7FFFu + ((u >> 16) & 1u)) >> 16;
  return (unsigned short)u;
}
__device__ __forceinline__ float bf2f(unsigned short v){
  return __uint_as_float(((unsigned)v) << 16);
}

// wave64 max of packed u64 via DPP. Result valid in lane 63.
__device__ __forceinline__ u64 wave_max_dpp(u64 k){
#define DPPSTEP(ctrl) {                                                        \
    unsigned lo = (unsigned)k, hi = (unsigned)(k >> 32);                       \
    unsigned olo = (unsigned)__builtin_amdgcn_update_dpp(0, (int)lo, ctrl, 0xf, 0xf, true); \
    unsigned ohi = (unsigned)__builtin_amdgcn_update_dpp(0, (int)hi, ctrl, 0xf, 0xf, true); \
    u64 o = (((u64)ohi) << 32) | olo;                                          \
    if (o > k) k = o; }
  DPPSTEP(0x111)
  DPPSTEP(0x112)
  DPPSTEP(0x114)
  DPPSTEP(0x118)
  DPPSTEP(0x142)
  DPPSTEP(0x143)
#undef DPPSTEP
  return k;
}

__device__ __forceinline__ unsigned p1b2(unsigned v){
  v &= 0x3FFu;
  v = (v | (v << 16)) & 0x030000FFu;
  v = (v | (v << 8))  & 0x0300F00Fu;
  v = (v | (v << 4))  & 0x030C30C3u;
  v = (v | (v << 2))  & 0x09249249u;
  return v;
}

// ---------------------------------------------------------------------------
// Kernel 1 (fused): morton sort (blocks 0..7) + transpose points (4096 blocks)
//                   + lin_w convert (2080 blocks) + sync-counter init.
// ---------------------------------------------------------------------------
#define TRB 4096
#define CVB 2080
__global__ __launch_bounds__(1024) void prep_kernel(
    const float* __restrict__ xyz, const float* __restrict__ pts,
    const float* __restrict__ lw,
    float* __restrict__ sx, float* __restrict__ sy, float* __restrict__ sz,
    int* __restrict__ sorig, unsigned short* __restrict__ ptsT,
    unsigned short* __restrict__ lwout, unsigned* __restrict__ psync){
  __shared__ __align__(16) char smem[65536];
  const int bid = blockIdx.x, t = threadIdx.x;
  if (bid < NB){
    // ---- morton bitonic sort ----
    u64* arr = (u64*)smem;
    const int b = bid;
    if (t == 0){ psync[b] = 0; if (b == 0) psync[8] = 0; }
    const float* xp = xyz + (size_t)b * 3 * NN;
#pragma unroll
    for (int j = 0; j < 8; j++){
      int n = t + j * 1024;
      float x = xp[n], y = xp[NN + n], z = xp[2 * NN + n];
      unsigned qx = (unsigned)fminf(1023.f, fmaxf(0.f, (x + 6.f) * 85.25f));
      unsigned qy = (unsigned)fminf(1023.f, fmaxf(0.f, (y + 6.f) * 85.25f));
      unsigned qz = (unsigned)fminf(1023.f, fmaxf(0.f, (z + 6.f) * 85.25f));
      unsigned key = (p1b2(qz) << 2) | (p1b2(qy) << 1) | p1b2(qx);
      arr[n] = (((u64)key) << 13) | (unsigned)n;
    }
    __syncthreads();
    for (int k = 2; k <= NN; k <<= 1){
      for (int j = k >> 1; j >= 1; j >>= 1){
#pragma unroll
        for (int pi = 0; pi < 4; pi++){
          int p = t + pi * 1024;
          int lo = ((p & ~(j - 1)) << 1) | (p & (j - 1));
          int hi = lo | j;
          bool asc = (lo & k) == 0;
          u64 a = arr[lo], c = arr[hi];
          if (asc ? (a > c) : (c > a)){ arr[lo] = c; arr[hi] = a; }
        }
        __syncthreads();
      }
    }
#pragma unroll
    for (int j = 0; j < 8; j++){
      int n = t + j * 1024;
      int orig = (int)(arr[n] & 8191u);
      sx[(size_t)b * NN + n] = xp[orig];
      sy[(size_t)b * NN + n] = xp[NN + orig];
      sz[(size_t)b * NN + n] = xp[2 * NN + orig];
      sorig[(size_t)b * NN + n] = orig;
    }
  } else if (bid < NB + TRB){
    // ---- transpose points [B,256,8192] f32 -> [B,8192,256] bf16 ----
    float (*tile)[65] = (float(*)[65])smem;
    const int r = bid - NB;
    const int n0 = (r & 127) * 64;
    const int d0 = ((r >> 7) & 3) * 64;
    const int b  = r >> 9;
    const int tx = t & 63, ty = t >> 6;
    const float* src = pts + ((size_t)b * ND + d0) * NN + n0;
#pragma unroll
    for (int j = 0; j < 4; j++){
      int d = ty + j * 16;
      tile[d][tx] = src[(size_t)d * NN + tx];
    }
    __syncthreads();
    unsigned short* dst = ptsT + ((size_t)b * NN + n0) * ND + d0;
#pragma unroll
    for (int j = 0; j < 4; j++){
      int n = ty + j * 16;
      dst[(size_t)n * ND + tx] = f2bf(tile[tx][n]);
    }
  } else {
    // ---- lin_w [512,4144] f32 -> [512,4160] bf16 (pad zero) ----
    int i = (bid - NB - TRB) * 1024 + t;
    if (i < OUTCH * KPAD){
      int o = i / KPAD, f = i - o * KPAD;
      float v = (f < WNET * INCH) ? lw[(size_t)o * (WNET * INCH) + f] : 0.f;
      lwout[i] = f2bf(v);
    }
  }
}

// ---------------------------------------------------------------------------
// radix-select helper (wave 0 only)
// ---------------------------------------------------------------------------
__device__ __forceinline__ void find_bin64(const unsigned* hist, unsigned r,
                                           unsigned* outB, unsigned* outC, int lane){
  unsigned h0 = hist[lane * 4 + 0], h1 = hist[lane * 4 + 1];
  unsigned h2 = hist[lane * 4 + 2], h3 = hist[lane * 4 + 3];
  unsigned s4 = h0 + h1 + h2 + h3;
  unsigned sc = s4;
#pragma unroll
  for (int off = 1; off < 64; off <<= 1){
    unsigned o = __shfl_up(sc, off, 64);
    if (lane >= off) sc += o;
  }
  unsigned cum = sc - s4;
  if (cum < r && cum + h0 >= r){ *outB = lane * 4 + 0; *outC = cum; } cum += h0;
  if (cum < r && cum + h1 >= r){ *outB = lane * 4 + 1; *outC = cum; } cum += h1;
  if (cum < r && cum + h2 >= r){ *outB = lane * 4 + 2; *outC = cum; } cum += h2;
  if (cum < r && cum + h3 >= r){ *outB = lane * 4 + 3; *outC = cum; } cum += h3;
}

// ---------------------------------------------------------------------------
// Kernel 2 (mega): blocks 0..7 = FPS (producer). blocks 8..247 = workers
// (consumer: kNN + WeightNet + aggregation per query, work-stealing queue).
// All 248 blocks co-resident (147KB LDS -> 1 block/CU, 248 <= 256 CUs).
// ---------------------------------------------------------------------------
struct WkScal { int selcnt, candcnt; unsigned info[4]; unsigned g; float nq[3]; };

__global__ __launch_bounds__(1024) void mega_kernel(
    const float* __restrict__ xyz,
    const float* __restrict__ sxg, const float* __restrict__ syg,
    const float* __restrict__ szg, const int* __restrict__ sorigg,
    float* __restrict__ out0, float* __restrict__ out2, float* wnew,
    const unsigned short* __restrict__ ptsT,
    const float* __restrict__ w1, const float* __restrict__ b1,
    const float* __restrict__ w2, const float* __restrict__ b2,
    const float* __restrict__ w3, const float* __restrict__ b3,
    unsigned short* __restrict__ agg, unsigned* psync){
  __shared__ __align__(16) char smem[147488];
  const int t = threadIdx.x;

  if (blockIdx.x < NB){
    // ================= FPS producer =================
#pragma clang fp contract(off)
    float4v* pxyz = (float4v*)smem;                // 131072 B
    u64* seq  = (u64*)(smem + 131072);             // 16384 B
    u64* slot = (u64*)(smem + 147456);             // 24 B
    int* ppos0 = (int*)(smem + 147480);
    const int b = blockIdx.x;
    const int lane = t & 63, w = t >> 6;
    const int base = w * 512 + lane * 8;
    const float* gx = sxg + (size_t)b * NN;
    const float* gy = syg + (size_t)b * NN;
    const float* gz = szg + (size_t)b * NN;
    const int*   go = sorigg + (size_t)b * NN;

    float x[8], y[8], z[8], ld[8]; int so[8];
#pragma unroll
    for (int j = 0; j < 8; j++){
      int n = base + j;
      x[j] = gx[n]; y[j] = gy[n]; z[j] = gz[n]; so[j] = go[n];
      pxyz[n] = (float4v){x[j], y[j], z[j], 0.f};
      if (so[j] == 0) *ppos0 = n;
      ld[j] = 1e10f;
    }
    if (t < 3) slot[t] = 0;
    float mnx = x[0], mxx = x[0], mny = y[0], mxy = y[0], mnz = z[0], mxz = z[0];
#pragma unroll
    for (int j = 1; j < 8; j++){
      mnx = fminf(mnx, x[j]); mxx = fmaxf(mxx, x[j]);
      mny = fminf(mny, y[j]); mxy = fmaxf(mxy, y[j]);
      mnz = fminf(mnz, z[j]); mxz = fmaxf(mxz, z[j]);
    }
    const float ccx = (mnx + mxx) * 0.5f, ccy = (mny + mxy) * 0.5f, ccz = (mnz + mxz) * 0.5f;
    float R2 = 0.f;
#pragma unroll
    for (int j = 0; j < 8; j++){
      float dx = x[j] - ccx, dy = y[j] - ccy, dz = z[j] - ccz;
      R2 = fmaxf(R2, (dx * dx + dy * dy) + dz * dz);
    }
    const float R = sqrtf(R2) * 1.001f + 1e-7f;
    float thr = 3e38f;
    u64 wkey = 0;
    __syncthreads();

    int pos = *ppos0;
    float4v c4 = pxyz[pos];
    float cx = c4[0], cy = c4[1], cz = c4[2];
    if (t == 0) seq[0] = (((u64)8191) << 13) | (unsigned)pos;   // orig=0

    for (int i = 1; i < NPOINT; i++){
      float qdx = cx - ccx, qdy = cy - ccy, qdz = cz - ccz;
      float q = (qdx * qdx + qdy * qdy) + qdz * qdz;
      if (__any(q < thr)){
        float bv = -1.f; int bo = 0, bp = 0;
#pragma unroll
        for (int j = 0; j < 8; j++){
          float dx = x[j] - cx, dy = y[j] - cy, dz = z[j] - cz;
          float d  = (dx * dx + dy * dy) + dz * dz;     // numpy order, no fma
          float nd = fminf(ld[j], d);
          ld[j] = nd;
          bool better = (nd > bv) || (nd == bv && so[j] < bo);
          bv = better ? nd : bv;
          bo = better ? so[j] : bo;
          bp = better ? (base + j) : bp;
        }
        float sr = sqrtf(bv) * 1.001f + R;
        thr = sr * sr;
        u64 k2 = (((u64)__float_as_uint(bv)) << 26) | (((u64)(8191 - bo)) << 13) | (unsigned)bp;
        wkey = wave_max_dpp(k2);
      }
      if (lane == 63) atomicMax((u64*)&slot[i % 3], wkey);
      if (t == 0) slot[(i + 1) % 3] = 0;
      __syncthreads();
      u64 v = slot[i % 3];
      if ((i & 31) == 0){           // publish winners [i-32, i-1]
        if (t < 32){
          int w2 = i - 32 + t;
          u64 sv = seq[w2];
          float4v pv = pxyz[(int)(sv & 8191u)];
          float* wp = wnew + ((size_t)b * NPOINT + w2) * 3;
          wp[0] = pv[0]; wp[1] = pv[1]; wp[2] = pv[2];
        }
        if (t == 0)
          __hip_atomic_store(&psync[b], (unsigned)i, __ATOMIC_RELEASE, __HIP_MEMORY_SCOPE_AGENT);
      }
      pos = (int)(v & 8191u);
      float4v n4 = pxyz[pos];
      cx = n4[0]; cy = n4[1]; cz = n4[2];
      if (t == 0) seq[i] = v;
    }
    __syncthreads();
    for (int k = t; k < NPOINT; k += 1024){
      u64 v = seq[k];
      int p = (int)(v & 8191u);
      int orig = 8191 - (int)((v >> 13) & 8191u);
      float4v pv = pxyz[p];
      out2[b * NPOINT + k] = (float)orig;
      out0[(size_t)b * 3 * NPOINT + k]              = pv[0];
      out0[(size_t)b * 3 * NPOINT + NPOINT + k]     = pv[1];
      out0[(size_t)b * 3 * NPOINT + 2 * NPOINT + k] = pv[2];
      float* wp = wnew + ((size_t)b * NPOINT + k) * 3;
      wp[0] = pv[0]; wp[1] = pv[1]; wp[2] = pv[2];
    }
    __syncthreads();
    if (t == 0)
      __hip_atomic_store(&psync[b], (unsigned)NPOINT, __ATOMIC_RELEASE, __HIP_MEMORY_SCOPE_AGENT);
    return;
  }

  // ================= worker: kNN + agg per query =================
  unsigned* key  = (unsigned*)smem;                    // 32768
  float (*feat)[257] = (float(*)[257])(smem + 32768);  // 32896
  float (*wgt)[16]   = (float(*)[16])(smem + 65664);   // 2048
  float (*xyzn)[4]   = (float(*)[4])(smem + 67712);    // 512
  unsigned* hist  = (unsigned*)(smem + 68224);         // 1024
  unsigned* candk = (unsigned*)(smem + 69248);         // 1024
  int* candi      = (int*)(smem + 70272);              // 1024
  int* s_sel      = (int*)(smem + 71296);              // 192
  WkScal* sc      = (WkScal*)(smem + 71488);

  while (true){
    if (t == 0){
      unsigned g = __hip_atomic_fetch_add(&psync[8], 1u, __ATOMIC_RELAXED, __HIP_MEMORY_SCOPE_AGENT);
      sc->g = g;
      if (g < (unsigned)(NB * NPOINT)){
        unsigned bq = g & 7u, sq = g >> 3;
        while (__hip_atomic_load(&psync[bq], __ATOMIC_ACQUIRE, __HIP_MEMORY_SCOPE_AGENT) <= sq)
          __builtin_amdgcn_s_sleep(8);
        float* wp = wnew + ((size_t)bq * NPOINT + sq) * 3;
        sc->nq[0] = __hip_atomic_load(wp + 0, __ATOMIC_RELAXED, __HIP_MEMORY_SCOPE_AGENT);
        sc->nq[1] = __hip_atomic_load(wp + 1, __ATOMIC_RELAXED, __HIP_MEMORY_SCOPE_AGENT);
        sc->nq[2] = __hip_atomic_load(wp + 2, __ATOMIC_RELAXED, __HIP_MEMORY_SCOPE_AGENT);
      }
      sc->selcnt = 0; sc->candcnt = 0;
    }
    if (t < 256) hist[t] = 0;
    __syncthreads();
    unsigned g = sc->g;
    if (g >= (unsigned)(NB * NPOINT)) break;
    const int bq = (int)(g & 7u), sq = (int)(g >> 3);
    const int q = bq * NPOINT + sq;
    const float qx = sc->nq[0], qy = sc->nq[1], qz = sc->nq[2];
    const float qq = qx * qx + qy * qy + qz * qz;
    const float* xp = xyz + (size_t)bq * 3 * NN;

    // ---- keys ----
#pragma unroll 2
    for (int j = 0; j < 8; j++){
      int n = t + j * 1024;
      float px = xp[n], py = xp[NN + n], pz = xp[2 * NN + n];
      float pp = px * px + py * py + pz * pz;
      float d  = qq + pp - 2.f * (qx * px + qy * py + qz * pz);
      unsigned u = __float_as_uint(d);
      u ^= (u & 0x80000000u) ? 0xFFFFFFFFu : 0x80000000u;
      key[n] = u;
    }
    __syncthreads();
#pragma unroll 2
    for (int j = 0; j < 8; j++)
      atomicAdd(&hist[key[t + j * 1024] >> 24], 1u);
    __syncthreads();
    if (t < 64) find_bin64(hist, NSAMPLE, &sc->info[0], &sc->info[1], t);
    __syncthreads();
    unsigned B1 = sc->info[0], c0 = sc->info[1];
    if (t < 256) hist[t] = 0;
    __syncthreads();
#pragma unroll 2
    for (int j = 0; j < 8; j++){
      unsigned u = key[t + j * 1024];
      if ((u >> 24) == B1) atomicAdd(&hist[(u >> 16) & 0xFFu], 1u);
    }
    __syncthreads();
    if (t < 64) find_bin64(hist, NSAMPLE - c0, &sc->info[2], &sc->info[3], t);
    __syncthreads();
    unsigned T16 = (B1 << 8) | sc->info[2];
    int c01 = (int)(c0 + sc->info[3]);
#pragma unroll 2
    for (int j = 0; j < 8; j++){
      int n = t + j * 1024;
      unsigned k16 = key[n] >> 16;
      if (k16 < T16){
        int p = atomicAdd(&sc->selcnt, 1);
        s_sel[p] = n;
      } else if (k16 == T16){
        int p = atomicAdd(&sc->candcnt, 1);
        if (p < 256){ candk[p] = key[n]; candi[p] = n; }
      }
    }
    __syncthreads();
    const int m = NSAMPLE - c01;
    const int L = sc->candcnt;
    if (t < 64){
      u64 prev = 0;
      for (int r = 0; r < m; r++){
        u64 best = ~0ULL;
        if (L <= 256){
          for (int j = t; j < L; j += 64){
            u64 pk = (((u64)candk[j]) << 32) | (unsigned)candi[j];
            if (pk > prev && pk < best) best = pk;
          }
        } else {
          for (int j = 0; j < 128; j++){
            int n = t + j * 64;
            unsigned u = key[n];
            if ((u >> 16) == T16){
              u64 pk = (((u64)u) << 32) | (unsigned)n;
              if (pk > prev && pk < best) best = pk;
            }
          }
        }
#pragma unroll
        for (int off = 32; off > 0; off >>= 1){
          u64 o = __shfl_down(best, off, 64);
          if (o < best) best = o;
        }
        best = __shfl(best, 0, 64);
        if (t == 0) s_sel[c01 + r] = (int)(best & 0xFFFFFFFFu);
        prev = best;
      }
    }
    __syncthreads();

    // ---- WeightNet + gather ----
    if (t < 32){
      int n = s_sel[t];
      float xn = xp[n] - qx, yn = xp[NN + n] - qy, zn = xp[2 * NN + n] - qz;
      xyzn[t][0] = xn; xyzn[t][1] = yn; xyzn[t][2] = zn;
      float h1[8], h2[8];
#pragma unroll
      for (int i = 0; i < 8; i++)
        h1[i] = fmaxf(0.f, w1[i * 3] * xn + w1[i * 3 + 1] * yn + w1[i * 3 + 2] * zn + b1[i]);
#pragma unroll
      for (int i = 0; i < 8; i++){
        float a = b2[i];
#pragma unroll
        for (int j = 0; j < 8; j++) a += w2[i * 8 + j] * h1[j];
        h2[i] = fmaxf(0.f, a);
      }
#pragma unroll
      for (int i = 0; i < 16; i++){
        float a = b3[i];
#pragma unroll
        for (int j = 0; j < 8; j++) a += w3[i * 8 + j] * h2[j];
        wgt[t][i] = fmaxf(0.f, a);
      }
    }
    {
      int row = t >> 5, col = t & 31;
      const uint4* src = (const uint4*)(ptsT + ((size_t)bq * NN + s_sel[row]) * ND) + col;
      uint4 v = *src;
      float* dstf = &feat[row][col * 8];
      dstf[0] = bf2f((unsigned short)(v.x & 0xFFFF)); dstf[1] = bf2f((unsigned short)(v.x >> 16));
      dstf[2] = bf2f((unsigned short)(v.y & 0xFFFF)); dstf[3] = bf2f((unsigned short)(v.y >> 16));
      dstf[4] = bf2f((unsigned short)(v.z & 0xFFFF)); dstf[5] = bf2f((unsigned short)(v.z >> 16));
      dstf[6] = bf2f((unsigned short)(v.w & 0xFFFF)); dstf[7] = bf2f((unsigned short)(v.w >> 16));
    }
    __syncthreads();
    if (t < INCH){
      const float* npb; int stride;
      if (t < 3){ npb = &xyzn[0][t]; stride = 4; }
      else      { npb = &feat[0][t - 3]; stride = 257; }
      float acc[16];
#pragma unroll
      for (int i = 0; i < 16; i++) acc[i] = 0.f;
      for (int k = 0; k < 32; k++){
        float v = npb[k * stride];
        const float4v* wr = (const float4v*)(&wgt[k][0]);
        float4v a0 = wr[0], a1 = wr[1], a2 = wr[2], a3 = wr[3];
        acc[0]  += v * a0[0]; acc[1]  += v * a0[1]; acc[2]  += v * a0[2]; acc[3]  += v * a0[3];
        acc[4]  += v * a1[0]; acc[5]  += v * a1[1]; acc[6]  += v * a1[2]; acc[7]  += v * a1[3];
        acc[8]  += v * a2[0]; acc[9]  += v * a2[1]; acc[10] += v * a2[2]; acc[11] += v * a2[3];
        acc[12] += v * a3[0]; acc[13] += v * a3[1]; acc[14] += v * a3[2]; acc[15] += v * a3[3];
      }
      unsigned r[8];
#pragma unroll
      for (int p = 0; p < 8; p++)
        r[p] = (unsigned)f2bf(acc[2 * p]) | ((unsigned)f2bf(acc[2 * p + 1]) << 16);
      uint4* dst = (uint4*)(agg + (size_t)q * KPAD + t * WNET);
      uint4 v0 = {r[0], r[1], r[2], r[3]};
      uint4 v1 = {r[4], r[5], r[6], r[7]};
      dst[0] = v0; dst[1] = v1;
    }
    if (t == INCH){   // zero the K pad
      uint4 z = {0, 0, 0, 0};
      uint4* dst = (uint4*)(agg + (size_t)q * KPAD + WNET * INCH);
      dst[0] = z; dst[1] = z;
    }
    __syncthreads();
  }
}

// ---------------------------------------------------------------------------
// Kernel 3: GEMM Out[16384,512] = Agg * lin_w^T + bias, LeakyReLU,
//           transposed store to [B,512,2048].
// ---------------------------------------------------------------------------
#define BM 128
#define BN 128
#define BK 64
__global__ __launch_bounds__(256) void gemm_kernel(
    const unsigned short* __restrict__ A, const unsigned short* __restrict__ W,
    const float* __restrict__ bias, float* __restrict__ out1){
  __shared__ short __align__(16) As[BM * BK];
  __shared__ short __align__(16) Ws[BN * BK];
  const int t = threadIdx.x;
  const int m0 = blockIdx.x * BM;
  const int n0 = blockIdx.y * BN;
  const int wave = t >> 6, lane = t & 63;
  const int wm = (wave >> 1) * 64, wn = (wave & 1) * 64;
  const int lrow = lane & 15, quad = lane >> 4;
  float4v acc[4][4];
#pragma unroll
  for (int i = 0; i < 4; i++)
#pragma unroll
    for (int j = 0; j < 4; j++) acc[i][j] = (float4v){0.f, 0.f, 0.f, 0.f};

  for (int k0 = 0; k0 < KPAD; k0 += BK){
#pragma unroll
    for (int j = 0; j < 4; j++){
      int chunk = t + 256 * j;
      int row = chunk >> 3, c = chunk & 7;
      uint4 v = *(const uint4*)(A + (size_t)(m0 + row) * KPAD + k0 + c * 8);
      *(uint4*)&As[chunk * 8] = v;
    }
#pragma unroll
    for (int j = 0; j < 4; j++){
      int chunk = t + 256 * j;
      int row = chunk >> 3, c = chunk & 7;
      uint4 v = *(const uint4*)(W + (size_t)(n0 + row) * KPAD + k0 + c * 8);
      *(uint4*)&Ws[chunk * 8] = v;
    }
    __syncthreads();
#pragma unroll
    for (int kk = 0; kk < 2; kk++){
      short8 a[4], w[4];
      int kof = kk * 32 + quad * 8;
#pragma unroll
      for (int i = 0; i < 4; i++){
        a[i] = *(const short8*)&As[(wm + i * 16 + lrow) * BK + kof];
        w[i] = *(const short8*)&Ws[(wn + i * 16 + lrow) * BK + kof];
      }
#pragma unroll
      for (int i = 0; i < 4; i++)
#pragma unroll
        for (int j = 0; j < 4; j++)
          acc[i][j] = __builtin_amdgcn_mfma_f32_16x16x32_bf16(a[i], w[j], acc[i][j], 0, 0, 0);
    }
    __syncthreads();
  }
#pragma unroll
  for (int i = 0; i < 4; i++){
#pragma unroll
    for (int j = 0; j < 4; j++){
      int m = m0 + wm + i * 16 + quad * 4;
      int n = n0 + wn + j * 16 + lrow;
      float bv = bias[n];
      int bb = m >> 11, s = m & 2047;
      float* dst = out1 + ((size_t)bb * OUTCH + n) * NPOINT + s;
      float4v v = acc[i][j];
      float4v r;
#pragma unroll
      for (int e = 0; e < 4; e++){
        float x = v[e] + bv;
        r[e] = x > 0.f ? x : 0.1f * x;
      }
      *(float4v*)dst = r;
    }
  }
}

// ---------------------------------------------------------------------------
extern "C" void kernel_launch(void* const* d_in, const int* in_sizes, int n_in,
                              void* d_out, int out_size, void* d_ws, size_t ws_size,
                              hipStream_t stream) {
  const float* xyz    = (const float*)d_in[0];
  const float* points = (const float*)d_in[1];
  const float* w1 = (const float*)d_in[2];
  const float* b1 = (const float*)d_in[3];
  const float* w2 = (const float*)d_in[4];
  const float* b2 = (const float*)d_in[5];
  const float* w3 = (const float*)d_in[6];
  const float* b3 = (const float*)d_in[7];
  const float* lin_w = (const float*)d_in[8];
  const float* lin_b = (const float*)d_in[9];

  float* out0 = (float*)d_out;
  float* out1 = out0 + (size_t)NB * 3 * NPOINT;
  float* out2 = out1 + (size_t)NB * OUTCH * NPOINT;

  char* ws = (char*)d_ws;
  float* ws_newxyz = (float*)ws;                                   size_t o = (size_t)NB * NPOINT * 3 * 4;
  unsigned short* ws_ptsT = (unsigned short*)(ws + o);             o += (size_t)NB * NN * ND * 2;
  unsigned short* ws_lw = (unsigned short*)(ws + o);               o += (size_t)OUTCH * KPAD * 2;
  unsigned short* ws_agg = (unsigned short*)(ws + o);              o += (size_t)NB * NPOINT * KPAD * 2;
  float* ws_sx = (float*)(ws + o);                                 o += (size_t)NB * NN * 4;
  float* ws_sy = (float*)(ws + o);                                 o += (size_t)NB * NN * 4;
  float* ws_sz = (float*)(ws + o);                                 o += (size_t)NB * NN * 4;
  int*   ws_so = (int*)(ws + o);                                   o += (size_t)NB * NN * 4;
  unsigned* ws_psync = (unsigned*)(ws + o);                        o += 64;

  prep_kernel<<<NB + TRB + CVB, 1024, 0, stream>>>(
      xyz, points, lin_w, ws_sx, ws_sy, ws_sz, ws_so, ws_ptsT, ws_lw, ws_psync);
  mega_kernel<<<248, 1024, 0, stream>>>(
      xyz, ws_sx, ws_sy, ws_sz, ws_so, out0, out2, ws_newxyz, ws_ptsT,
      w1, b1, w2, b2, w3, b3, ws_agg, ws_psync);
  gemm_kernel<<<dim3(NB * NPOINT / BM, OUTCH / BN), 256, 0, stream>>>(ws_agg, ws_lw, lin_b, out1);
}